// Round 10
// baseline (1417.538 us; speedup 1.0000x reference)
//
#include <hip/hip_runtime.h>

#define N_NODES 50000
#define N_EDGES 400000
#define EPSV 1e-5f
#define SCAN_BLK 49          // ceil(50000/1024)
#define SCAN_PAD (49 * 1024) // 50176

// ---------------- node encoder: out = relu(in2 @ W1 + b1) @ W2 + b2 -----------
__global__ __launch_bounds__(256) void encode_kernel(
    const float* __restrict__ in2, const float* __restrict__ W1,
    const float* __restrict__ b1, const float* __restrict__ W2,
    const float* __restrict__ b2, float* __restrict__ out, int nrows)
{
  int t = blockIdx.x * 256 + threadIdx.x;
  int row = t >> 4;
  int d0 = t & 15;
  if (row >= nrows) return;
  float x0 = in2[row * 2 + 0], x1 = in2[row * 2 + 1];
  float h[16];
#pragma unroll
  for (int j = 0; j < 16; ++j)
    h[j] = fmaxf(fmaf(x0, W1[j], fmaf(x1, W1[16 + j], b1[j])), 0.f);
#pragma unroll
  for (int q = 0; q < 4; ++q) {
    int d = d0 + q * 16;
    float a = b2[d];
#pragma unroll
    for (int j = 0; j < 16; ++j) a = fmaf(h[j], W2[j * 64 + d], a);
    out[(size_t)row * 64 + d] = a;
  }
}

// ------- edge encoder, permuted: E_f[p] = enc(e[csr_f[p].x]) ------------------
__global__ __launch_bounds__(256) void encode_perm_kernel(
    const float* __restrict__ in2, const float* __restrict__ W1,
    const float* __restrict__ b1, const float* __restrict__ W2,
    const float* __restrict__ b2, const int2* __restrict__ csr_f,
    float* __restrict__ out)
{
  int t = blockIdx.x * 256 + threadIdx.x;
  int row = t >> 4;
  int d0 = t & 15;
  if (row >= N_EDGES) return;
  int orig = csr_f[row].x;
  float x0 = in2[orig * 2 + 0], x1 = in2[orig * 2 + 1];
  float h[16];
#pragma unroll
  for (int j = 0; j < 16; ++j)
    h[j] = fmaxf(fmaf(x0, W1[j], fmaf(x1, W1[16 + j], b1[j])), 0.f);
#pragma unroll
  for (int q = 0; q < 4; ++q) {
    int d = d0 + q * 16;
    float a = b2[d];
#pragma unroll
    for (int j = 0; j < 16; ++j) a = fmaf(h[j], W2[j * 64 + d], a);
    out[(size_t)row * 64 + d] = a;
  }
}

// ---------------- CSR build ----------------
__global__ __launch_bounds__(256) void hist_kernel(
    const int* __restrict__ src, const int* __restrict__ dst,
    int* __restrict__ cnt_f, int* __restrict__ cnt_b)
{
  int t = blockIdx.x * 256 + threadIdx.x;
  if (t >= N_EDGES) return;
  atomicAdd(&cnt_f[dst[t]], 1);
  atomicAdd(&cnt_b[src[t]], 1);
}

__global__ __launch_bounds__(1024) void scanA_kernel(
    const int* __restrict__ cnt_f, const int* __restrict__ cnt_b,
    int* __restrict__ part, int* __restrict__ bsum)
{
  int dir = blockIdx.x / SCAN_BLK;
  int blk = blockIdx.x % SCAN_BLK;
  const int* cnt = dir ? cnt_b : cnt_f;
  int t = threadIdx.x;
  int idx = blk * 1024 + t;
  int v = (idx < N_NODES) ? cnt[idx] : 0;
  __shared__ int sh[1024];
  sh[t] = v;
  __syncthreads();
  for (int o = 1; o < 1024; o <<= 1) {
    int u = (t >= o) ? sh[t - o] : 0;
    __syncthreads();
    sh[t] += u;
    __syncthreads();
  }
  part[dir * SCAN_PAD + idx] = sh[t] - v;
  if (t == 1023) bsum[dir * SCAN_BLK + blk] = sh[1023];
}

// parallel scan of the 2x49 block sums (one wave per direction)
__global__ __launch_bounds__(128) void scanB_kernel(
    int* __restrict__ bsum, int* __restrict__ off_f, int* __restrict__ off_b)
{
  int dir = threadIdx.x >> 6;
  int i = threadIdx.x & 63;
  int v = (i < SCAN_BLK) ? bsum[dir * SCAN_BLK + i] : 0;
  int s = v;
#pragma unroll
  for (int o = 1; o < 64; o <<= 1) {
    int u = __shfl_up(s, o, 64);
    if (i >= o) s += u;
  }
  if (i < SCAN_BLK) bsum[dir * SCAN_BLK + i] = s - v;
  if (i == SCAN_BLK - 1) {
    if (dir == 0) off_f[N_NODES] = s;
    else off_b[N_NODES] = s;
  }
}

__global__ __launch_bounds__(1024) void scanC_kernel(
    const int* __restrict__ part, const int* __restrict__ bsum,
    int* __restrict__ off_f, int* __restrict__ off_b,
    int* __restrict__ cur_f, int* __restrict__ cur_b)
{
  int dir = blockIdx.x / SCAN_BLK;
  int blk = blockIdx.x % SCAN_BLK;
  int t = threadIdx.x;
  int idx = blk * 1024 + t;
  if (idx >= N_NODES) return;
  int v = part[dir * SCAN_PAD + idx] + bsum[dir * SCAN_BLK + blk];
  if (dir == 0) { off_f[idx] = v; cur_f[idx] = v; }
  else { off_b[idx] = v; cur_b[idx] = v; }
}

__global__ __launch_bounds__(256) void fill_kernel(
    const int* __restrict__ src, const int* __restrict__ dst,
    int* __restrict__ cur_f, int* __restrict__ cur_b,
    int2* __restrict__ csr_f, int2* __restrict__ csr_b)
{
  int t = blockIdx.x * 256 + threadIdx.x;
  if (t >= N_EDGES) return;
  int dv = dst[t], sv = src[t];
  int p = atomicAdd(&cur_f[dv], 1);
  csr_f[p] = make_int2(t, sv);
  int q = atomicAdd(&cur_b[sv], 1);
  csr_b[q] = make_int2(t, dv);
}

__global__ __launch_bounds__(256) void sort_kernel(
    const int* __restrict__ off_f, const int* __restrict__ off_b,
    int2* __restrict__ csr_f, int2* __restrict__ csr_b)
{
  int t = blockIdx.x * 256 + threadIdx.x;
  int n;
  int2* csr;
  const int* off;
  if (t < N_NODES) { n = t; csr = csr_f; off = off_f; }
  else if (t < 2 * N_NODES) { n = t - N_NODES; csr = csr_b; off = off_b; }
  else return;
  int b = off[n], e = off[n + 1];
  for (int i = b + 1; i < e; ++i) {
    int2 key = csr[i];
    int j = i - 1;
    while (j >= b && csr[j].x > key.x) { csr[j + 1] = csr[j]; --j; }
    csr[j + 1] = key;
  }
}

// --- aux: inv_f + src_f; dst_f expansion; csr_b.x -> fwd position remap -------
__global__ __launch_bounds__(256) void aux_inv_kernel(
    const int2* __restrict__ csr_f, int* __restrict__ inv_f,
    int* __restrict__ src_f)
{
  int p = blockIdx.x * 256 + threadIdx.x;
  if (p >= N_EDGES) return;
  int2 c = csr_f[p];
  inv_f[c.x] = p;
  src_f[p] = c.y;
}

__global__ __launch_bounds__(256) void aux_dst_kernel(
    const int* __restrict__ off_f, int* __restrict__ dst_f)
{
  int n = blockIdx.x * 256 + threadIdx.x;
  if (n >= N_NODES) return;
  int b = off_f[n], e = off_f[n + 1];
  for (int p = b; p < e; ++p) dst_f[p] = n;
}

__global__ __launch_bounds__(256) void aux_remap_kernel(
    const int* __restrict__ inv_f, int2* __restrict__ csr_b)
{
  int q = blockIdx.x * 256 + threadIdx.x;
  if (q >= N_EDGES) return;
  int2 c = csr_b[q];
  csr_b[q] = make_int2(inv_f[c.x], c.y);
}

// =====================================================================
// 8x8-lane outer-product micro-GEMM: 32 rows x 64 cols per wave.
// lane -> (r8 = lane&7: rows 4*r8..+3, c8 = lane>>3: cols 8*c8..+7)
// E tile transposed in LDS; W streamed from global (L1-resident).
// edge kernels: split-K double-pass halves LDS -> 2x resident waves.
// =====================================================================

// ------- node GEMMs: ONE shared X tile, 5 waves = 5 matrices ------------------
__global__ __launch_bounds__(320, 6) void node_gemm_kernel(
    const float* __restrict__ X,
    const float* __restrict__ A1, const float* __restrict__ A2,
    const float* __restrict__ A3, const float* __restrict__ B1,
    const float* __restrict__ B2,
    const float* __restrict__ bA1, const float* __restrict__ bA2,
    const float* __restrict__ bA3, const float* __restrict__ bB1,
    const float* __restrict__ bB2,
    float* __restrict__ NA, int l)
{
  __shared__ float tl[64 * 36];
  int wid = threadIdx.x >> 6;
  int lane = threadIdx.x & 63;
  int row0 = blockIdx.x * 32;
  // cooperative stage + transpose: X[row][c] -> tl[c*36 + r]
  for (int i = threadIdx.x; i < 32 * 16; i += 320) {
    int r = i >> 4, c4 = (i & 15) * 4;
    int row = row0 + r;
    float4 v = (row < N_NODES)
                   ? *reinterpret_cast<const float4*>(&X[(size_t)row * 64 + c4])
                   : make_float4(0.f, 0.f, 0.f, 0.f);
    tl[(c4 + 0) * 36 + r] = v.x;
    tl[(c4 + 1) * 36 + r] = v.y;
    tl[(c4 + 2) * 36 + r] = v.z;
    tl[(c4 + 3) * 36 + r] = v.w;
  }
  __syncthreads();
  int r8 = lane & 7, c8 = lane >> 3;
  int col = 8 * c8;
  const float* W;
  const float* bb;
  if (wid == 0) { W = A1; bb = bA1; }
  else if (wid == 1) { W = A2; bb = bA2; }
  else if (wid == 2) { W = A3; bb = bA3; }
  else if (wid == 3) { W = B1; bb = bB1; }
  else { W = B2; bb = bB2; }
  W += l * 64 * 64;
  float acc[4][8];
#pragma unroll
  for (int i = 0; i < 4; ++i)
#pragma unroll
    for (int j = 0; j < 8; ++j) acc[i][j] = 0.f;
#pragma unroll 8
  for (int k = 0; k < 64; ++k) {
    float4 er = *reinterpret_cast<const float4*>(&tl[k * 36 + 4 * r8]);
    float4 w0 = *reinterpret_cast<const float4*>(&W[k * 64 + col]);
    float4 w1 = *reinterpret_cast<const float4*>(&W[k * 64 + col + 4]);
    float ev[4] = {er.x, er.y, er.z, er.w};
    float wv[8] = {w0.x, w0.y, w0.z, w0.w, w1.x, w1.y, w1.z, w1.w};
#pragma unroll
    for (int i = 0; i < 4; ++i)
#pragma unroll
      for (int j = 0; j < 8; ++j) acc[i][j] = fmaf(ev[i], wv[j], acc[i][j]);
  }
  float4 b0 = *reinterpret_cast<const float4*>(&bb[l * 64 + col]);
  float4 b1 = *reinterpret_cast<const float4*>(&bb[l * 64 + col + 4]);
  float* out = NA + (size_t)wid * N_NODES * 64;
#pragma unroll
  for (int i = 0; i < 4; ++i) {
    int row = row0 + 4 * r8 + i;
    if (row < N_NODES) {
      *reinterpret_cast<float4*>(&out[(size_t)row * 64 + col]) =
          make_float4(acc[i][0] + b0.x, acc[i][1] + b0.y, acc[i][2] + b0.z,
                      acc[i][3] + b0.w);
      *reinterpret_cast<float4*>(&out[(size_t)row * 64 + col + 4]) =
          make_float4(acc[i][4] + b1.x, acc[i][5] + b1.y, acc[i][6] + b1.z,
                      acc[i][7] + b1.w);
    }
  }
}

// ------- edge update (fwd-order E), split-K: e += relu(LN(...)) ---------------
__global__ __launch_bounds__(256, 6) void edge_update_kernel(
    const float* __restrict__ NA,
    const float* __restrict__ B3, const float* __restrict__ bB3,
    const float* __restrict__ ge, const float* __restrict__ be,
    const int* __restrict__ src_f, const int* __restrict__ dst_f,
    float* __restrict__ E64, int l)
{
  __shared__ float ett[4][32 * 36];  // 4.6KB/wave: split-K halves
  int wid = threadIdx.x >> 6;
  int lane = threadIdx.x & 63;
  int tile = blockIdx.x * 4 + wid;
  int e0 = tile * 32;
  int r8 = lane & 7, c8 = lane >> 3;
  int col = 8 * c8;
  float* tl = ett[wid];
  const float* W = B3 + l * 64 * 64;
  int kc = lane & 31;         // k column staged by this lane
  int rh = (lane >> 5) * 16;  // row half
  float acc[4][8];
#pragma unroll
  for (int i = 0; i < 4; ++i)
#pragma unroll
    for (int j = 0; j < 8; ++j) acc[i][j] = 0.f;
#pragma unroll
  for (int h = 0; h < 2; ++h) {
    int cb = 32 * h + kc;
    // stage half-K transposed: E[r][cb] -> tl[kc*36 + r]
#pragma unroll
    for (int rb = 0; rb < 4; ++rb) {
      int r = e0 + rh + 4 * rb;
      float v0 = E64[(size_t)(r + 0) * 64 + cb];
      float v1 = E64[(size_t)(r + 1) * 64 + cb];
      float v2 = E64[(size_t)(r + 2) * 64 + cb];
      float v3 = E64[(size_t)(r + 3) * 64 + cb];
      *reinterpret_cast<float4*>(&tl[kc * 36 + rh + 4 * rb]) =
          make_float4(v0, v1, v2, v3);
    }
#pragma unroll 8
    for (int kk = 0; kk < 32; ++kk) {
      int k = 32 * h + kk;
      float4 er = *reinterpret_cast<const float4*>(&tl[kk * 36 + 4 * r8]);
      float4 w0 = *reinterpret_cast<const float4*>(&W[k * 64 + col]);
      float4 w1 = *reinterpret_cast<const float4*>(&W[k * 64 + col + 4]);
      float ev[4] = {er.x, er.y, er.z, er.w};
      float wv[8] = {w0.x, w0.y, w0.z, w0.w, w1.x, w1.y, w1.z, w1.w};
#pragma unroll
      for (int i = 0; i < 4; ++i)
#pragma unroll
        for (int j = 0; j < 8; ++j) acc[i][j] = fmaf(ev[i], wv[j], acc[i][j]);
    }
  }
  const float* b1x = NA + (size_t)3 * N_NODES * 64;
  const float* b2x = NA + (size_t)4 * N_NODES * 64;
  float4 t0, t1;
  t0 = *reinterpret_cast<const float4*>(&bB3[l * 64 + col]);
  t1 = *reinterpret_cast<const float4*>(&bB3[l * 64 + col + 4]);
  float bbv[8] = {t0.x, t0.y, t0.z, t0.w, t1.x, t1.y, t1.z, t1.w};
  t0 = *reinterpret_cast<const float4*>(&ge[l * 64 + col]);
  t1 = *reinterpret_cast<const float4*>(&ge[l * 64 + col + 4]);
  float gev[8] = {t0.x, t0.y, t0.z, t0.w, t1.x, t1.y, t1.z, t1.w};
  t0 = *reinterpret_cast<const float4*>(&be[l * 64 + col]);
  t1 = *reinterpret_cast<const float4*>(&be[l * 64 + col + 4]);
  float bev[8] = {t0.x, t0.y, t0.z, t0.w, t1.x, t1.y, t1.z, t1.w};
#pragma unroll
  for (int i = 0; i < 4; ++i) {
    int row = e0 + 4 * r8 + i;
    int sv = src_f[row];
    int dv = dst_f[row];
    float4 g0 = *reinterpret_cast<const float4*>(&b1x[(size_t)sv * 64 + col]);
    float4 g1 = *reinterpret_cast<const float4*>(&b1x[(size_t)sv * 64 + col + 4]);
    float4 h0 = *reinterpret_cast<const float4*>(&b2x[(size_t)dv * 64 + col]);
    float4 h1 = *reinterpret_cast<const float4*>(&b2x[(size_t)dv * 64 + col + 4]);
    float4 o0 = *reinterpret_cast<const float4*>(&E64[(size_t)row * 64 + col]);
    float4 o1 = *reinterpret_cast<const float4*>(&E64[(size_t)row * 64 + col + 4]);
    float g1v[8] = {g0.x, g0.y, g0.z, g0.w, g1.x, g1.y, g1.z, g1.w};
    float g2v[8] = {h0.x, h0.y, h0.z, h0.w, h1.x, h1.y, h1.z, h1.w};
    float eov[8] = {o0.x, o0.y, o0.z, o0.w, o1.x, o1.y, o1.z, o1.w};
    float z[8];
    float s1 = 0.f, s2 = 0.f;
#pragma unroll
    for (int j = 0; j < 8; ++j) {
      z[j] = acc[i][j] + bbv[j] + g1v[j] + g2v[j];
      s1 += z[j];
      s2 = fmaf(z[j], z[j], s2);
    }
    s1 += __shfl_xor(s1, 8, 64);  s2 += __shfl_xor(s2, 8, 64);
    s1 += __shfl_xor(s1, 16, 64); s2 += __shfl_xor(s2, 16, 64);
    s1 += __shfl_xor(s1, 32, 64); s2 += __shfl_xor(s2, 32, 64);
    float mean = s1 * (1.f / 64.f);
    float var = fmaxf(s2 * (1.f / 64.f) - mean * mean, 0.f);
    float rstd = rsqrtf(var + EPSV);
    float o[8];
#pragma unroll
    for (int j = 0; j < 8; ++j)
      o[j] = eov[j] + fmaxf(fmaf((z[j] - mean) * rstd, gev[j], bev[j]), 0.f);
    *reinterpret_cast<float4*>(&E64[(size_t)row * 64 + col]) =
        make_float4(o[0], o[1], o[2], o[3]);
    *reinterpret_cast<float4*>(&E64[(size_t)row * 64 + col + 4]) =
        make_float4(o[4], o[5], o[6], o[7]);
  }
}

// ----- gated aggregation + node update; fwd E streams, bwd E gathers ----------
__global__ __launch_bounds__(256, 8) void aggregate_kernel(
    const float* __restrict__ NA, const float* __restrict__ E64,
    const int* __restrict__ off_f, const int* __restrict__ off_b,
    const int* __restrict__ src_f, const int2* __restrict__ csr_b,
    const float* __restrict__ gh, const float* __restrict__ bh,
    float* __restrict__ X, int l)
{
  int wave = threadIdx.x >> 6;
  int lane = threadIdx.x & 63;
  int n = blockIdx.x * 4 + wave;
  if (n >= N_NODES) return;
  const float* A1x = NA;
  const float* A2x = NA + (size_t)N_NODES * 64;
  const float* A3x = NA + (size_t)2 * N_NODES * 64;
  float xo = X[(size_t)n * 64 + lane];
  float a1v = A1x[(size_t)n * 64 + lane];
  float ghv = gh[l * 64 + lane];
  float bhv = bh[l * 64 + lane];
  int pf = off_f[n], pfe = off_f[n + 1];
  int pb = off_b[n], pbe = off_b[n + 1];
  float mf = 0.f, df = 0.f, mb = 0.f, db = 0.f;
#pragma unroll 4
  for (int p = pf; p < pfe; ++p) {
    float ev = E64[(size_t)p * 64 + lane];               // streaming (fwd order)
    float av = A2x[(size_t)src_f[p] * 64 + lane];
    float sg = __builtin_amdgcn_rcpf(1.f + __expf(-ev));
    mf = fmaf(sg, av, mf);
    df += sg;
  }
#pragma unroll 4
  for (int p = pb; p < pbe; ++p) {
    int2 c = csr_b[p];                                    // (fwd pos, dst node)
    float ev = E64[(size_t)c.x * 64 + lane];
    float av = A3x[(size_t)c.y * 64 + lane];
    float sg = __builtin_amdgcn_rcpf(1.f + __expf(-ev));
    mb = fmaf(sg, av, mb);
    db += sg;
  }
  float h = a1v + mf * __builtin_amdgcn_rcpf(df + EPSV) +
            mb * __builtin_amdgcn_rcpf(db + EPSV);
  float s1 = h, s2 = h * h;
#pragma unroll
  for (int m = 1; m < 64; m <<= 1) {
    s1 += __shfl_xor(s1, m, 64);
    s2 += __shfl_xor(s2, m, 64);
  }
  float mean = s1 * (1.f / 64.f);
  float var = fmaxf(s2 * (1.f / 64.f) - mean * mean, 0.f);
  float rstd = rsqrtf(var + EPSV);
  X[(size_t)n * 64 + lane] =
      xo + fmaxf(fmaf((h - mean) * rstd, ghv, bhv), 0.f);
}

// ------- predictor node projections: shared X tile, 2 waves = U,V -------------
__global__ __launch_bounds__(128, 8) void pred_node_kernel(
    const float* __restrict__ X, const float* __restrict__ pW1,
    float* __restrict__ U, float* __restrict__ V)
{
  __shared__ float tl[64 * 36];
  int wid = threadIdx.x >> 6;
  int lane = threadIdx.x & 63;
  int row0 = blockIdx.x * 32;
  for (int i = threadIdx.x; i < 32 * 16; i += 128) {
    int r = i >> 4, c4 = (i & 15) * 4;
    int row = row0 + r;
    float4 v = (row < N_NODES)
                   ? *reinterpret_cast<const float4*>(&X[(size_t)row * 64 + c4])
                   : make_float4(0.f, 0.f, 0.f, 0.f);
    tl[(c4 + 0) * 36 + r] = v.x;
    tl[(c4 + 1) * 36 + r] = v.y;
    tl[(c4 + 2) * 36 + r] = v.z;
    tl[(c4 + 3) * 36 + r] = v.w;
  }
  __syncthreads();
  int r8 = lane & 7, c8 = lane >> 3;
  int col = 8 * c8;
  const float* W = pW1 + (size_t)wid * 64 * 64;
  float acc[4][8];
#pragma unroll
  for (int i = 0; i < 4; ++i)
#pragma unroll
    for (int j = 0; j < 8; ++j) acc[i][j] = 0.f;
#pragma unroll 8
  for (int k = 0; k < 64; ++k) {
    float4 er = *reinterpret_cast<const float4*>(&tl[k * 36 + 4 * r8]);
    float4 w0 = *reinterpret_cast<const float4*>(&W[k * 64 + col]);
    float4 w1 = *reinterpret_cast<const float4*>(&W[k * 64 + col + 4]);
    float ev[4] = {er.x, er.y, er.z, er.w};
    float wv[8] = {w0.x, w0.y, w0.z, w0.w, w1.x, w1.y, w1.z, w1.w};
#pragma unroll
    for (int i = 0; i < 4; ++i)
#pragma unroll
      for (int j = 0; j < 8; ++j) acc[i][j] = fmaf(ev[i], wv[j], acc[i][j]);
  }
  float* out = wid ? V : U;
#pragma unroll
  for (int i = 0; i < 4; ++i) {
    int row = row0 + 4 * r8 + i;
    if (row < N_NODES) {
      *reinterpret_cast<float4*>(&out[(size_t)row * 64 + col]) =
          make_float4(acc[i][0], acc[i][1], acc[i][2], acc[i][3]);
      *reinterpret_cast<float4*>(&out[(size_t)row * 64 + col + 4]) =
          make_float4(acc[i][4], acc[i][5], acc[i][6], acc[i][7]);
    }
  }
}

// ------- predictor edge pass, split-K: out[orig] = relu(...)·pW2 + pb2 --------
__global__ __launch_bounds__(256, 6) void pred_edge_kernel(
    const float* __restrict__ U, const float* __restrict__ V,
    const float* __restrict__ E64,
    const int2* __restrict__ csr_f, const int* __restrict__ dst_f,
    const float* __restrict__ pW1, const float* __restrict__ pb1,
    const float* __restrict__ pW2, const float* __restrict__ pb2,
    float* __restrict__ out)
{
  __shared__ float ett[4][32 * 36];
  int wid = threadIdx.x >> 6;
  int lane = threadIdx.x & 63;
  int tile = blockIdx.x * 4 + wid;
  int e0 = tile * 32;
  int r8 = lane & 7, c8 = lane >> 3;
  int col = 8 * c8;
  float* tl = ett[wid];
  const float* W = pW1 + (size_t)128 * 64;
  int kc = lane & 31;
  int rh = (lane >> 5) * 16;
  float acc[4][8];
#pragma unroll
  for (int i = 0; i < 4; ++i)
#pragma unroll
    for (int j = 0; j < 8; ++j) acc[i][j] = 0.f;
#pragma unroll
  for (int h = 0; h < 2; ++h) {
    int cb = 32 * h + kc;
#pragma unroll
    for (int rb = 0; rb < 4; ++rb) {
      int r = e0 + rh + 4 * rb;
      float v0 = E64[(size_t)(r + 0) * 64 + cb];
      float v1 = E64[(size_t)(r + 1) * 64 + cb];
      float v2 = E64[(size_t)(r + 2) * 64 + cb];
      float v3 = E64[(size_t)(r + 3) * 64 + cb];
      *reinterpret_cast<float4*>(&tl[kc * 36 + rh + 4 * rb]) =
          make_float4(v0, v1, v2, v3);
    }
#pragma unroll 8
    for (int kk = 0; kk < 32; ++kk) {
      int k = 32 * h + kk;
      float4 er = *reinterpret_cast<const float4*>(&tl[kk * 36 + 4 * r8]);
      float4 w0 = *reinterpret_cast<const float4*>(&W[k * 64 + col]);
      float4 w1 = *reinterpret_cast<const float4*>(&W[k * 64 + col + 4]);
      float ev[4] = {er.x, er.y, er.z, er.w};
      float wv[8] = {w0.x, w0.y, w0.z, w0.w, w1.x, w1.y, w1.z, w1.w};
#pragma unroll
      for (int i = 0; i < 4; ++i)
#pragma unroll
        for (int j = 0; j < 8; ++j) acc[i][j] = fmaf(ev[i], wv[j], acc[i][j]);
    }
  }
  float4 t0, t1;
  t0 = *reinterpret_cast<const float4*>(&pb1[col]);
  t1 = *reinterpret_cast<const float4*>(&pb1[col + 4]);
  float pb1v[8] = {t0.x, t0.y, t0.z, t0.w, t1.x, t1.y, t1.z, t1.w};
  t0 = *reinterpret_cast<const float4*>(&pW2[col]);
  t1 = *reinterpret_cast<const float4*>(&pW2[col + 4]);
  float pw2v[8] = {t0.x, t0.y, t0.z, t0.w, t1.x, t1.y, t1.z, t1.w};
  float pb2v = pb2[0];
#pragma unroll
  for (int i = 0; i < 4; ++i) {
    int row = e0 + 4 * r8 + i;
    int2 cf = csr_f[row];
    int sv = cf.y;
    int dv = dst_f[row];
    float4 g0 = *reinterpret_cast<const float4*>(&U[(size_t)sv * 64 + col]);
    float4 g1 = *reinterpret_cast<const float4*>(&U[(size_t)sv * 64 + col + 4]);
    float4 h0 = *reinterpret_cast<const float4*>(&V[(size_t)dv * 64 + col]);
    float4 h1 = *reinterpret_cast<const float4*>(&V[(size_t)dv * 64 + col + 4]);
    float g1v[8] = {g0.x, g0.y, g0.z, g0.w, g1.x, g1.y, g1.z, g1.w};
    float g2v[8] = {h0.x, h0.y, h0.z, h0.w, h1.x, h1.y, h1.z, h1.w};
    float hsum = 0.f;
#pragma unroll
    for (int j = 0; j < 8; ++j) {
      float z = acc[i][j] + pb1v[j] + g1v[j] + g2v[j];
      hsum = fmaf(fmaxf(z, 0.f), pw2v[j], hsum);
    }
    hsum += __shfl_xor(hsum, 8, 64);
    hsum += __shfl_xor(hsum, 16, 64);
    hsum += __shfl_xor(hsum, 32, 64);
    if (c8 == 0) out[cf.x] = hsum + pb2v;
  }
}

extern "C" void kernel_launch(void* const* d_in, const int* in_sizes, int n_in,
                              void* d_out, int out_size, void* d_ws, size_t ws_size,
                              hipStream_t stream)
{
  const float* x = (const float*)d_in[0];
  const float* e = (const float*)d_in[1];
  const int* src = (const int*)d_in[2];
  const int* dst = (const int*)d_in[3];
  const float* neW1 = (const float*)d_in[4];
  const float* neb1 = (const float*)d_in[5];
  const float* neW2 = (const float*)d_in[6];
  const float* neb2 = (const float*)d_in[7];
  const float* eeW1 = (const float*)d_in[8];
  const float* eeb1 = (const float*)d_in[9];
  const float* eeW2 = (const float*)d_in[10];
  const float* eeb2 = (const float*)d_in[11];
  const float* A1 = (const float*)d_in[12];
  const float* bA1 = (const float*)d_in[13];
  const float* A2 = (const float*)d_in[14];
  const float* bA2 = (const float*)d_in[15];
  const float* A3 = (const float*)d_in[16];
  const float* bA3 = (const float*)d_in[17];
  const float* B1 = (const float*)d_in[18];
  const float* bB1 = (const float*)d_in[19];
  const float* B2 = (const float*)d_in[20];
  const float* bB2 = (const float*)d_in[21];
  const float* B3 = (const float*)d_in[22];
  const float* bB3 = (const float*)d_in[23];
  const float* ge = (const float*)d_in[24];
  const float* be = (const float*)d_in[25];
  const float* gh = (const float*)d_in[26];
  const float* bh = (const float*)d_in[27];
  const float* pW1 = (const float*)d_in[28];
  const float* pb1 = (const float*)d_in[29];
  const float* pW2 = (const float*)d_in[30];
  const float* pb2 = (const float*)d_in[31];

  char* ws = (char*)d_ws;
  float* X = (float*)ws;      ws += (size_t)N_NODES * 64 * 4;
  float* NA = (float*)ws;     ws += (size_t)5 * N_NODES * 64 * 4;
  float* E64 = (float*)ws;    ws += (size_t)N_EDGES * 64 * 4;  // fwd-CSR order
  int* cnt_f = (int*)ws;      ws += (size_t)N_NODES * 4;
  int* cnt_b = (int*)ws;      ws += (size_t)N_NODES * 4;
  int* off_f = (int*)ws;      ws += (size_t)(N_NODES + 1) * 4;
  int* off_b = (int*)ws;      ws += (size_t)(N_NODES + 1) * 4;
  int* cur_f = (int*)ws;      ws += (size_t)N_NODES * 4;
  int* cur_b = (int*)ws;      ws += (size_t)N_NODES * 4;
  int2* csr_f = (int2*)ws;    ws += (size_t)N_EDGES * 8;
  int2* csr_b = (int2*)ws;    ws += (size_t)N_EDGES * 8;
  int* part = (int*)ws;       ws += (size_t)2 * SCAN_PAD * 4;
  int* bsum = (int*)ws;       ws += (size_t)2 * SCAN_BLK * 4;
  int* inv_f = (int*)ws;      ws += (size_t)N_EDGES * 4;
  int* dst_f = (int*)ws;      ws += (size_t)N_EDGES * 4;
  int* src_f = (int*)ws;      ws += (size_t)N_EDGES * 4;
  // U,V reuse NA slots 3,4 (dead after the last edge_update)
  float* U = NA + (size_t)3 * N_NODES * 64;
  float* V = NA + (size_t)4 * N_NODES * 64;

  // CSR build first (edge encoder needs the permutation)
  hipMemsetAsync(cnt_f, 0, (size_t)2 * N_NODES * 4, stream);
  hist_kernel<<<(N_EDGES + 255) / 256, 256, 0, stream>>>(src, dst, cnt_f, cnt_b);
  scanA_kernel<<<2 * SCAN_BLK, 1024, 0, stream>>>(cnt_f, cnt_b, part, bsum);
  scanB_kernel<<<1, 128, 0, stream>>>(bsum, off_f, off_b);
  scanC_kernel<<<2 * SCAN_BLK, 1024, 0, stream>>>(part, bsum, off_f, off_b,
                                                  cur_f, cur_b);
  fill_kernel<<<(N_EDGES + 255) / 256, 256, 0, stream>>>(src, dst, cur_f, cur_b,
                                                         csr_f, csr_b);
  sort_kernel<<<(2 * N_NODES + 255) / 256, 256, 0, stream>>>(off_f, off_b, csr_f,
                                                             csr_b);
  aux_inv_kernel<<<(N_EDGES + 255) / 256, 256, 0, stream>>>(csr_f, inv_f, src_f);
  aux_dst_kernel<<<(N_NODES + 255) / 256, 256, 0, stream>>>(off_f, dst_f);
  aux_remap_kernel<<<(N_EDGES + 255) / 256, 256, 0, stream>>>(inv_f, csr_b);

  // encoders
  encode_kernel<<<(N_NODES * 16 + 255) / 256, 256, 0, stream>>>(
      x, neW1, neb1, neW2, neb2, X, N_NODES);
  encode_perm_kernel<<<(N_EDGES * 16 + 255) / 256, 256, 0, stream>>>(
      e, eeW1, eeb1, eeW2, eeb2, csr_f, E64);

  // layers
  const int NT = (N_NODES + 31) / 32;  // 1563
  for (int l = 0; l < 4; ++l) {
    node_gemm_kernel<<<NT, 320, 0, stream>>>(
        X, A1, A2, A3, B1, B2, bA1, bA2, bA3, bB1, bB2, NA, l);
    edge_update_kernel<<<N_EDGES / 128, 256, 0, stream>>>(NA, B3, bB3, ge, be,
                                                          src_f, dst_f, E64, l);
    aggregate_kernel<<<(N_NODES + 3) / 4, 256, 0, stream>>>(
        NA, E64, off_f, off_b, src_f, csr_b, gh, bh, X, l);
  }

  // predictor
  pred_node_kernel<<<NT, 128, 0, stream>>>(X, pW1, U, V);
  pred_edge_kernel<<<N_EDGES / 128, 256, 0, stream>>>(U, V, E64, csr_f, dst_f,
                                                      pW1, pb1, pW2, pb2,
                                                      (float*)d_out);
}

// Round 11
// 1147.230 us; speedup vs baseline: 1.2356x; 1.2356x over previous
//
#include <hip/hip_runtime.h>

#define N_NODES 50000
#define N_EDGES 400000
#define EPSV 1e-5f
#define SCAN_BLK 49          // ceil(50000/1024)
#define SCAN_PAD (49 * 1024) // 50176

// ---------------- node encoder: out = relu(in2 @ W1 + b1) @ W2 + b2 -----------
__global__ __launch_bounds__(256) void encode_kernel(
    const float* __restrict__ in2, const float* __restrict__ W1,
    const float* __restrict__ b1, const float* __restrict__ W2,
    const float* __restrict__ b2, float* __restrict__ out, int nrows)
{
  int t = blockIdx.x * 256 + threadIdx.x;
  int row = t >> 4;
  int d0 = t & 15;
  if (row >= nrows) return;
  float x0 = in2[row * 2 + 0], x1 = in2[row * 2 + 1];
  float h[16];
#pragma unroll
  for (int j = 0; j < 16; ++j)
    h[j] = fmaxf(fmaf(x0, W1[j], fmaf(x1, W1[16 + j], b1[j])), 0.f);
#pragma unroll
  for (int q = 0; q < 4; ++q) {
    int d = d0 + q * 16;
    float a = b2[d];
#pragma unroll
    for (int j = 0; j < 16; ++j) a = fmaf(h[j], W2[j * 64 + d], a);
    out[(size_t)row * 64 + d] = a;
  }
}

// ------- edge encoder, permuted: E_f[p] = enc(e[csr_f[p].x]) ------------------
__global__ __launch_bounds__(256) void encode_perm_kernel(
    const float* __restrict__ in2, const float* __restrict__ W1,
    const float* __restrict__ b1, const float* __restrict__ W2,
    const float* __restrict__ b2, const int2* __restrict__ csr_f,
    float* __restrict__ out)
{
  int t = blockIdx.x * 256 + threadIdx.x;
  int row = t >> 4;
  int d0 = t & 15;
  if (row >= N_EDGES) return;
  int orig = csr_f[row].x;
  float x0 = in2[orig * 2 + 0], x1 = in2[orig * 2 + 1];
  float h[16];
#pragma unroll
  for (int j = 0; j < 16; ++j)
    h[j] = fmaxf(fmaf(x0, W1[j], fmaf(x1, W1[16 + j], b1[j])), 0.f);
#pragma unroll
  for (int q = 0; q < 4; ++q) {
    int d = d0 + q * 16;
    float a = b2[d];
#pragma unroll
    for (int j = 0; j < 16; ++j) a = fmaf(h[j], W2[j * 64 + d], a);
    out[(size_t)row * 64 + d] = a;
  }
}

// ---------------- CSR build ----------------
__global__ __launch_bounds__(256) void hist_kernel(
    const int* __restrict__ src, const int* __restrict__ dst,
    int* __restrict__ cnt_f, int* __restrict__ cnt_b)
{
  int t = blockIdx.x * 256 + threadIdx.x;
  if (t >= N_EDGES) return;
  atomicAdd(&cnt_f[dst[t]], 1);
  atomicAdd(&cnt_b[src[t]], 1);
}

__global__ __launch_bounds__(1024) void scanA_kernel(
    const int* __restrict__ cnt_f, const int* __restrict__ cnt_b,
    int* __restrict__ part, int* __restrict__ bsum)
{
  int dir = blockIdx.x / SCAN_BLK;
  int blk = blockIdx.x % SCAN_BLK;
  const int* cnt = dir ? cnt_b : cnt_f;
  int t = threadIdx.x;
  int idx = blk * 1024 + t;
  int v = (idx < N_NODES) ? cnt[idx] : 0;
  __shared__ int sh[1024];
  sh[t] = v;
  __syncthreads();
  for (int o = 1; o < 1024; o <<= 1) {
    int u = (t >= o) ? sh[t - o] : 0;
    __syncthreads();
    sh[t] += u;
    __syncthreads();
  }
  part[dir * SCAN_PAD + idx] = sh[t] - v;
  if (t == 1023) bsum[dir * SCAN_BLK + blk] = sh[1023];
}

// parallel scan of the 2x49 block sums (one wave per direction)
__global__ __launch_bounds__(128) void scanB_kernel(
    int* __restrict__ bsum, int* __restrict__ off_f, int* __restrict__ off_b)
{
  int dir = threadIdx.x >> 6;
  int i = threadIdx.x & 63;
  int v = (i < SCAN_BLK) ? bsum[dir * SCAN_BLK + i] : 0;
  int s = v;
#pragma unroll
  for (int o = 1; o < 64; o <<= 1) {
    int u = __shfl_up(s, o, 64);
    if (i >= o) s += u;
  }
  if (i < SCAN_BLK) bsum[dir * SCAN_BLK + i] = s - v;
  if (i == SCAN_BLK - 1) {
    if (dir == 0) off_f[N_NODES] = s;
    else off_b[N_NODES] = s;
  }
}

__global__ __launch_bounds__(1024) void scanC_kernel(
    const int* __restrict__ part, const int* __restrict__ bsum,
    int* __restrict__ off_f, int* __restrict__ off_b,
    int* __restrict__ cur_f, int* __restrict__ cur_b)
{
  int dir = blockIdx.x / SCAN_BLK;
  int blk = blockIdx.x % SCAN_BLK;
  int t = threadIdx.x;
  int idx = blk * 1024 + t;
  if (idx >= N_NODES) return;
  int v = part[dir * SCAN_PAD + idx] + bsum[dir * SCAN_BLK + blk];
  if (dir == 0) { off_f[idx] = v; cur_f[idx] = v; }
  else { off_b[idx] = v; cur_b[idx] = v; }
}

__global__ __launch_bounds__(256) void fill_kernel(
    const int* __restrict__ src, const int* __restrict__ dst,
    int* __restrict__ cur_f, int* __restrict__ cur_b,
    int2* __restrict__ csr_f, int2* __restrict__ csr_b)
{
  int t = blockIdx.x * 256 + threadIdx.x;
  if (t >= N_EDGES) return;
  int dv = dst[t], sv = src[t];
  int p = atomicAdd(&cur_f[dv], 1);
  csr_f[p] = make_int2(t, sv);
  int q = atomicAdd(&cur_b[sv], 1);
  csr_b[q] = make_int2(t, dv);
}

__global__ __launch_bounds__(256) void sort_kernel(
    const int* __restrict__ off_f, const int* __restrict__ off_b,
    int2* __restrict__ csr_f, int2* __restrict__ csr_b)
{
  int t = blockIdx.x * 256 + threadIdx.x;
  int n;
  int2* csr;
  const int* off;
  if (t < N_NODES) { n = t; csr = csr_f; off = off_f; }
  else if (t < 2 * N_NODES) { n = t - N_NODES; csr = csr_b; off = off_b; }
  else return;
  int b = off[n], e = off[n + 1];
  for (int i = b + 1; i < e; ++i) {
    int2 key = csr[i];
    int j = i - 1;
    while (j >= b && csr[j].x > key.x) { csr[j + 1] = csr[j]; --j; }
    csr[j + 1] = key;
  }
}

// --- aux: inv_f + src_f; dst_f expansion; csr_b.x -> fwd position remap -------
__global__ __launch_bounds__(256) void aux_inv_kernel(
    const int2* __restrict__ csr_f, int* __restrict__ inv_f,
    int* __restrict__ src_f)
{
  int p = blockIdx.x * 256 + threadIdx.x;
  if (p >= N_EDGES) return;
  int2 c = csr_f[p];
  inv_f[c.x] = p;
  src_f[p] = c.y;
}

__global__ __launch_bounds__(256) void aux_dst_kernel(
    const int* __restrict__ off_f, int* __restrict__ dst_f)
{
  int n = blockIdx.x * 256 + threadIdx.x;
  if (n >= N_NODES) return;
  int b = off_f[n], e = off_f[n + 1];
  for (int p = b; p < e; ++p) dst_f[p] = n;
}

__global__ __launch_bounds__(256) void aux_remap_kernel(
    const int* __restrict__ inv_f, int2* __restrict__ csr_b)
{
  int q = blockIdx.x * 256 + threadIdx.x;
  if (q >= N_EDGES) return;
  int2 c = csr_b[q];
  csr_b[q] = make_int2(inv_f[c.x], c.y);
}

// =====================================================================
// micro-GEMM kernels. node/pred_node: 8x8-lane grid, 32 rows/wave.
// edge kernels: 4x16-lane grid, 16 rows/wave, LDS pitch 20 ->
// 20,480B/block = exactly 8 blocks/CU (100% wave occupancy).
// Single-phase schedule: stage -> K-loop -> epilogue (short re-read gap).
// =====================================================================

// ------- node GEMMs: ONE shared X tile, 5 waves = 5 matrices ------------------
__global__ __launch_bounds__(320, 6) void node_gemm_kernel(
    const float* __restrict__ X,
    const float* __restrict__ A1, const float* __restrict__ A2,
    const float* __restrict__ A3, const float* __restrict__ B1,
    const float* __restrict__ B2,
    const float* __restrict__ bA1, const float* __restrict__ bA2,
    const float* __restrict__ bA3, const float* __restrict__ bB1,
    const float* __restrict__ bB2,
    float* __restrict__ NA, int l)
{
  __shared__ float tl[64 * 36];
  int wid = threadIdx.x >> 6;
  int lane = threadIdx.x & 63;
  int row0 = blockIdx.x * 32;
  // cooperative stage + transpose: X[row][c] -> tl[c*36 + r]
  for (int i = threadIdx.x; i < 32 * 16; i += 320) {
    int r = i >> 4, c4 = (i & 15) * 4;
    int row = row0 + r;
    float4 v = (row < N_NODES)
                   ? *reinterpret_cast<const float4*>(&X[(size_t)row * 64 + c4])
                   : make_float4(0.f, 0.f, 0.f, 0.f);
    tl[(c4 + 0) * 36 + r] = v.x;
    tl[(c4 + 1) * 36 + r] = v.y;
    tl[(c4 + 2) * 36 + r] = v.z;
    tl[(c4 + 3) * 36 + r] = v.w;
  }
  __syncthreads();
  int r8 = lane & 7, c8 = lane >> 3;
  int col = 8 * c8;
  const float* W;
  const float* bb;
  if (wid == 0) { W = A1; bb = bA1; }
  else if (wid == 1) { W = A2; bb = bA2; }
  else if (wid == 2) { W = A3; bb = bA3; }
  else if (wid == 3) { W = B1; bb = bB1; }
  else { W = B2; bb = bB2; }
  W += l * 64 * 64;
  float acc[4][8];
#pragma unroll
  for (int i = 0; i < 4; ++i)
#pragma unroll
    for (int j = 0; j < 8; ++j) acc[i][j] = 0.f;
#pragma unroll 8
  for (int k = 0; k < 64; ++k) {
    float4 er = *reinterpret_cast<const float4*>(&tl[k * 36 + 4 * r8]);
    float4 w0 = *reinterpret_cast<const float4*>(&W[k * 64 + col]);
    float4 w1 = *reinterpret_cast<const float4*>(&W[k * 64 + col + 4]);
    float ev[4] = {er.x, er.y, er.z, er.w};
    float wv[8] = {w0.x, w0.y, w0.z, w0.w, w1.x, w1.y, w1.z, w1.w};
#pragma unroll
    for (int i = 0; i < 4; ++i)
#pragma unroll
      for (int j = 0; j < 8; ++j) acc[i][j] = fmaf(ev[i], wv[j], acc[i][j]);
  }
  float4 b0 = *reinterpret_cast<const float4*>(&bb[l * 64 + col]);
  float4 b1 = *reinterpret_cast<const float4*>(&bb[l * 64 + col + 4]);
  float* out = NA + (size_t)wid * N_NODES * 64;
#pragma unroll
  for (int i = 0; i < 4; ++i) {
    int row = row0 + 4 * r8 + i;
    if (row < N_NODES) {
      *reinterpret_cast<float4*>(&out[(size_t)row * 64 + col]) =
          make_float4(acc[i][0] + b0.x, acc[i][1] + b0.y, acc[i][2] + b0.z,
                      acc[i][3] + b0.w);
      *reinterpret_cast<float4*>(&out[(size_t)row * 64 + col + 4]) =
          make_float4(acc[i][4] + b1.x, acc[i][5] + b1.y, acc[i][6] + b1.z,
                      acc[i][7] + b1.w);
    }
  }
}

// ------- edge update (fwd-order E): 16 rows/wave, 4x16 lane grid --------------
__global__ __launch_bounds__(256, 8) void edge_update_kernel(
    const float* __restrict__ NA,
    const float* __restrict__ B3, const float* __restrict__ bB3,
    const float* __restrict__ ge, const float* __restrict__ be,
    const int* __restrict__ src_f, const int* __restrict__ dst_f,
    float* __restrict__ E64, int l)
{
  __shared__ float ett[4][64 * 20];  // 5KB/wave -> 8 blocks/CU
  int wid = threadIdx.x >> 6;
  int lane = threadIdx.x & 63;
  int tile = blockIdx.x * 4 + wid;
  int e0 = tile * 16;  // 16 rows per wave
  int r4 = lane & 3, c16 = lane >> 2;
  int col = 4 * c16;
  float* tl = ett[wid];
  // stage + transpose (lane = column k): E[r][lane] -> tl[lane*20 + r]
#pragma unroll
  for (int rb = 0; rb < 4; ++rb) {
    int r = e0 + 4 * rb;
    float v0 = E64[(size_t)(r + 0) * 64 + lane];
    float v1 = E64[(size_t)(r + 1) * 64 + lane];
    float v2 = E64[(size_t)(r + 2) * 64 + lane];
    float v3 = E64[(size_t)(r + 3) * 64 + lane];
    *reinterpret_cast<float4*>(&tl[lane * 20 + 4 * rb]) =
        make_float4(v0, v1, v2, v3);
  }
  const float* W = B3 + l * 64 * 64;
  float acc[4][4];
#pragma unroll
  for (int i = 0; i < 4; ++i)
#pragma unroll
    for (int j = 0; j < 4; ++j) acc[i][j] = 0.f;
#pragma unroll 8
  for (int k = 0; k < 64; ++k) {
    float4 er = *reinterpret_cast<const float4*>(&tl[k * 20 + 4 * r4]);
    float4 w0 = *reinterpret_cast<const float4*>(&W[k * 64 + col]);
    float ev[4] = {er.x, er.y, er.z, er.w};
    float wv[4] = {w0.x, w0.y, w0.z, w0.w};
#pragma unroll
    for (int i = 0; i < 4; ++i)
#pragma unroll
      for (int j = 0; j < 4; ++j) acc[i][j] = fmaf(ev[i], wv[j], acc[i][j]);
  }
  const float* b1x = NA + (size_t)3 * N_NODES * 64;
  const float* b2x = NA + (size_t)4 * N_NODES * 64;
  float4 t0;
  t0 = *reinterpret_cast<const float4*>(&bB3[l * 64 + col]);
  float bbv[4] = {t0.x, t0.y, t0.z, t0.w};
  t0 = *reinterpret_cast<const float4*>(&ge[l * 64 + col]);
  float gev[4] = {t0.x, t0.y, t0.z, t0.w};
  t0 = *reinterpret_cast<const float4*>(&be[l * 64 + col]);
  float bev[4] = {t0.x, t0.y, t0.z, t0.w};
#pragma unroll
  for (int i = 0; i < 4; ++i) {
    int row = e0 + 4 * r4 + i;
    int sv = src_f[row];
    int dv = dst_f[row];
    float4 g0 = *reinterpret_cast<const float4*>(&b1x[(size_t)sv * 64 + col]);
    float4 h0 = *reinterpret_cast<const float4*>(&b2x[(size_t)dv * 64 + col]);
    float4 o0 = *reinterpret_cast<const float4*>(&E64[(size_t)row * 64 + col]);
    float g1v[4] = {g0.x, g0.y, g0.z, g0.w};
    float g2v[4] = {h0.x, h0.y, h0.z, h0.w};
    float eov[4] = {o0.x, o0.y, o0.z, o0.w};
    float z[4];
    float s1 = 0.f, s2 = 0.f;
#pragma unroll
    for (int j = 0; j < 4; ++j) {
      z[j] = acc[i][j] + bbv[j] + g1v[j] + g2v[j];
      s1 += z[j];
      s2 = fmaf(z[j], z[j], s2);
    }
    // reduce across the 16 lanes (same r4): lane bits 2..5
    s1 += __shfl_xor(s1, 4, 64);  s2 += __shfl_xor(s2, 4, 64);
    s1 += __shfl_xor(s1, 8, 64);  s2 += __shfl_xor(s2, 8, 64);
    s1 += __shfl_xor(s1, 16, 64); s2 += __shfl_xor(s2, 16, 64);
    s1 += __shfl_xor(s1, 32, 64); s2 += __shfl_xor(s2, 32, 64);
    float mean = s1 * (1.f / 64.f);
    float var = fmaxf(s2 * (1.f / 64.f) - mean * mean, 0.f);
    float rstd = rsqrtf(var + EPSV);
    float o[4];
#pragma unroll
    for (int j = 0; j < 4; ++j)
      o[j] = eov[j] + fmaxf(fmaf((z[j] - mean) * rstd, gev[j], bev[j]), 0.f);
    *reinterpret_cast<float4*>(&E64[(size_t)row * 64 + col]) =
        make_float4(o[0], o[1], o[2], o[3]);
  }
}

// ----- gated aggregation + node update; fwd E streams, bwd E gathers ----------
__global__ __launch_bounds__(256) void aggregate_kernel(
    const float* __restrict__ NA, const float* __restrict__ E64,
    const int* __restrict__ off_f, const int* __restrict__ off_b,
    const int* __restrict__ src_f, const int2* __restrict__ csr_b,
    const float* __restrict__ gh, const float* __restrict__ bh,
    float* __restrict__ X, int l)
{
  int wave = threadIdx.x >> 6;
  int lane = threadIdx.x & 63;
  int n = blockIdx.x * 4 + wave;
  if (n >= N_NODES) return;
  const float* A1x = NA;
  const float* A2x = NA + (size_t)N_NODES * 64;
  const float* A3x = NA + (size_t)2 * N_NODES * 64;
  float xo = X[(size_t)n * 64 + lane];
  float a1v = A1x[(size_t)n * 64 + lane];
  float ghv = gh[l * 64 + lane];
  float bhv = bh[l * 64 + lane];
  int pf = off_f[n], pfe = off_f[n + 1];
  int pb = off_b[n], pbe = off_b[n + 1];
  float mf = 0.f, df = 0.f, mb = 0.f, db = 0.f;
#pragma unroll 4
  for (int p = pf; p < pfe; ++p) {
    float ev = E64[(size_t)p * 64 + lane];               // streaming (fwd order)
    float av = A2x[(size_t)src_f[p] * 64 + lane];
    float sg = __builtin_amdgcn_rcpf(1.f + __expf(-ev));
    mf = fmaf(sg, av, mf);
    df += sg;
  }
#pragma unroll 4
  for (int p = pb; p < pbe; ++p) {
    int2 c = csr_b[p];                                    // (fwd pos, dst node)
    float ev = E64[(size_t)c.x * 64 + lane];
    float av = A3x[(size_t)c.y * 64 + lane];
    float sg = __builtin_amdgcn_rcpf(1.f + __expf(-ev));
    mb = fmaf(sg, av, mb);
    db += sg;
  }
  float h = a1v + mf * __builtin_amdgcn_rcpf(df + EPSV) +
            mb * __builtin_amdgcn_rcpf(db + EPSV);
  float s1 = h, s2 = h * h;
#pragma unroll
  for (int m = 1; m < 64; m <<= 1) {
    s1 += __shfl_xor(s1, m, 64);
    s2 += __shfl_xor(s2, m, 64);
  }
  float mean = s1 * (1.f / 64.f);
  float var = fmaxf(s2 * (1.f / 64.f) - mean * mean, 0.f);
  float rstd = rsqrtf(var + EPSV);
  X[(size_t)n * 64 + lane] =
      xo + fmaxf(fmaf((h - mean) * rstd, ghv, bhv), 0.f);
}

// ------- predictor node projections: shared X tile, 2 waves = U,V -------------
__global__ __launch_bounds__(128, 8) void pred_node_kernel(
    const float* __restrict__ X, const float* __restrict__ pW1,
    float* __restrict__ U, float* __restrict__ V)
{
  __shared__ float tl[64 * 36];
  int wid = threadIdx.x >> 6;
  int lane = threadIdx.x & 63;
  int row0 = blockIdx.x * 32;
  for (int i = threadIdx.x; i < 32 * 16; i += 128) {
    int r = i >> 4, c4 = (i & 15) * 4;
    int row = row0 + r;
    float4 v = (row < N_NODES)
                   ? *reinterpret_cast<const float4*>(&X[(size_t)row * 64 + c4])
                   : make_float4(0.f, 0.f, 0.f, 0.f);
    tl[(c4 + 0) * 36 + r] = v.x;
    tl[(c4 + 1) * 36 + r] = v.y;
    tl[(c4 + 2) * 36 + r] = v.z;
    tl[(c4 + 3) * 36 + r] = v.w;
  }
  __syncthreads();
  int r8 = lane & 7, c8 = lane >> 3;
  int col = 8 * c8;
  const float* W = pW1 + (size_t)wid * 64 * 64;
  float acc[4][8];
#pragma unroll
  for (int i = 0; i < 4; ++i)
#pragma unroll
    for (int j = 0; j < 8; ++j) acc[i][j] = 0.f;
#pragma unroll 8
  for (int k = 0; k < 64; ++k) {
    float4 er = *reinterpret_cast<const float4*>(&tl[k * 36 + 4 * r8]);
    float4 w0 = *reinterpret_cast<const float4*>(&W[k * 64 + col]);
    float4 w1 = *reinterpret_cast<const float4*>(&W[k * 64 + col + 4]);
    float ev[4] = {er.x, er.y, er.z, er.w};
    float wv[8] = {w0.x, w0.y, w0.z, w0.w, w1.x, w1.y, w1.z, w1.w};
#pragma unroll
    for (int i = 0; i < 4; ++i)
#pragma unroll
      for (int j = 0; j < 8; ++j) acc[i][j] = fmaf(ev[i], wv[j], acc[i][j]);
  }
  float* out = wid ? V : U;
#pragma unroll
  for (int i = 0; i < 4; ++i) {
    int row = row0 + 4 * r8 + i;
    if (row < N_NODES) {
      *reinterpret_cast<float4*>(&out[(size_t)row * 64 + col]) =
          make_float4(acc[i][0], acc[i][1], acc[i][2], acc[i][3]);
      *reinterpret_cast<float4*>(&out[(size_t)row * 64 + col + 4]) =
          make_float4(acc[i][4], acc[i][5], acc[i][6], acc[i][7]);
    }
  }
}

// ------- predictor edge pass: 16 rows/wave, 4x16 lane grid --------------------
__global__ __launch_bounds__(256, 8) void pred_edge_kernel(
    const float* __restrict__ U, const float* __restrict__ V,
    const float* __restrict__ E64,
    const int2* __restrict__ csr_f, const int* __restrict__ dst_f,
    const float* __restrict__ pW1, const float* __restrict__ pb1,
    const float* __restrict__ pW2, const float* __restrict__ pb2,
    float* __restrict__ out)
{
  __shared__ float ett[4][64 * 20];
  int wid = threadIdx.x >> 6;
  int lane = threadIdx.x & 63;
  int tile = blockIdx.x * 4 + wid;
  int e0 = tile * 16;
  int r4 = lane & 3, c16 = lane >> 2;
  int col = 4 * c16;
  float* tl = ett[wid];
#pragma unroll
  for (int rb = 0; rb < 4; ++rb) {
    int r = e0 + 4 * rb;
    float v0 = E64[(size_t)(r + 0) * 64 + lane];
    float v1 = E64[(size_t)(r + 1) * 64 + lane];
    float v2 = E64[(size_t)(r + 2) * 64 + lane];
    float v3 = E64[(size_t)(r + 3) * 64 + lane];
    *reinterpret_cast<float4*>(&tl[lane * 20 + 4 * rb]) =
        make_float4(v0, v1, v2, v3);
  }
  const float* W = pW1 + (size_t)128 * 64;
  float acc[4][4];
#pragma unroll
  for (int i = 0; i < 4; ++i)
#pragma unroll
    for (int j = 0; j < 4; ++j) acc[i][j] = 0.f;
#pragma unroll 8
  for (int k = 0; k < 64; ++k) {
    float4 er = *reinterpret_cast<const float4*>(&tl[k * 20 + 4 * r4]);
    float4 w0 = *reinterpret_cast<const float4*>(&W[k * 64 + col]);
    float ev[4] = {er.x, er.y, er.z, er.w};
    float wv[4] = {w0.x, w0.y, w0.z, w0.w};
#pragma unroll
    for (int i = 0; i < 4; ++i)
#pragma unroll
      for (int j = 0; j < 4; ++j) acc[i][j] = fmaf(ev[i], wv[j], acc[i][j]);
  }
  float4 t0;
  t0 = *reinterpret_cast<const float4*>(&pb1[col]);
  float pb1v[4] = {t0.x, t0.y, t0.z, t0.w};
  t0 = *reinterpret_cast<const float4*>(&pW2[col]);
  float pw2v[4] = {t0.x, t0.y, t0.z, t0.w};
  float pb2v = pb2[0];
#pragma unroll
  for (int i = 0; i < 4; ++i) {
    int row = e0 + 4 * r4 + i;
    int2 cf = csr_f[row];
    int sv = cf.y;
    int dv = dst_f[row];
    float4 g0 = *reinterpret_cast<const float4*>(&U[(size_t)sv * 64 + col]);
    float4 h0 = *reinterpret_cast<const float4*>(&V[(size_t)dv * 64 + col]);
    float g1v[4] = {g0.x, g0.y, g0.z, g0.w};
    float g2v[4] = {h0.x, h0.y, h0.z, h0.w};
    float hsum = 0.f;
#pragma unroll
    for (int j = 0; j < 4; ++j) {
      float z = acc[i][j] + pb1v[j] + g1v[j] + g2v[j];
      hsum = fmaf(fmaxf(z, 0.f), pw2v[j], hsum);
    }
    hsum += __shfl_xor(hsum, 4, 64);
    hsum += __shfl_xor(hsum, 8, 64);
    hsum += __shfl_xor(hsum, 16, 64);
    hsum += __shfl_xor(hsum, 32, 64);
    if (c16 == 0) out[cf.x] = hsum + pb2v;
  }
}

extern "C" void kernel_launch(void* const* d_in, const int* in_sizes, int n_in,
                              void* d_out, int out_size, void* d_ws, size_t ws_size,
                              hipStream_t stream)
{
  const float* x = (const float*)d_in[0];
  const float* e = (const float*)d_in[1];
  const int* src = (const int*)d_in[2];
  const int* dst = (const int*)d_in[3];
  const float* neW1 = (const float*)d_in[4];
  const float* neb1 = (const float*)d_in[5];
  const float* neW2 = (const float*)d_in[6];
  const float* neb2 = (const float*)d_in[7];
  const float* eeW1 = (const float*)d_in[8];
  const float* eeb1 = (const float*)d_in[9];
  const float* eeW2 = (const float*)d_in[10];
  const float* eeb2 = (const float*)d_in[11];
  const float* A1 = (const float*)d_in[12];
  const float* bA1 = (const float*)d_in[13];
  const float* A2 = (const float*)d_in[14];
  const float* bA2 = (const float*)d_in[15];
  const float* A3 = (const float*)d_in[16];
  const float* bA3 = (const float*)d_in[17];
  const float* B1 = (const float*)d_in[18];
  const float* bB1 = (const float*)d_in[19];
  const float* B2 = (const float*)d_in[20];
  const float* bB2 = (const float*)d_in[21];
  const float* B3 = (const float*)d_in[22];
  const float* bB3 = (const float*)d_in[23];
  const float* ge = (const float*)d_in[24];
  const float* be = (const float*)d_in[25];
  const float* gh = (const float*)d_in[26];
  const float* bh = (const float*)d_in[27];
  const float* pW1 = (const float*)d_in[28];
  const float* pb1 = (const float*)d_in[29];
  const float* pW2 = (const float*)d_in[30];
  const float* pb2 = (const float*)d_in[31];

  char* ws = (char*)d_ws;
  float* X = (float*)ws;      ws += (size_t)N_NODES * 64 * 4;
  float* NA = (float*)ws;     ws += (size_t)5 * N_NODES * 64 * 4;
  float* E64 = (float*)ws;    ws += (size_t)N_EDGES * 64 * 4;  // fwd-CSR order
  int* cnt_f = (int*)ws;      ws += (size_t)N_NODES * 4;
  int* cnt_b = (int*)ws;      ws += (size_t)N_NODES * 4;
  int* off_f = (int*)ws;      ws += (size_t)(N_NODES + 1) * 4;
  int* off_b = (int*)ws;      ws += (size_t)(N_NODES + 1) * 4;
  int* cur_f = (int*)ws;      ws += (size_t)N_NODES * 4;
  int* cur_b = (int*)ws;      ws += (size_t)N_NODES * 4;
  int2* csr_f = (int2*)ws;    ws += (size_t)N_EDGES * 8;
  int2* csr_b = (int2*)ws;    ws += (size_t)N_EDGES * 8;
  int* part = (int*)ws;       ws += (size_t)2 * SCAN_PAD * 4;
  int* bsum = (int*)ws;       ws += (size_t)2 * SCAN_BLK * 4;
  int* inv_f = (int*)ws;      ws += (size_t)N_EDGES * 4;
  int* dst_f = (int*)ws;      ws += (size_t)N_EDGES * 4;
  int* src_f = (int*)ws;      ws += (size_t)N_EDGES * 4;
  // U,V reuse NA slots 3,4 (dead after the last edge_update)
  float* U = NA + (size_t)3 * N_NODES * 64;
  float* V = NA + (size_t)4 * N_NODES * 64;

  // CSR build first (edge encoder needs the permutation)
  hipMemsetAsync(cnt_f, 0, (size_t)2 * N_NODES * 4, stream);
  hist_kernel<<<(N_EDGES + 255) / 256, 256, 0, stream>>>(src, dst, cnt_f, cnt_b);
  scanA_kernel<<<2 * SCAN_BLK, 1024, 0, stream>>>(cnt_f, cnt_b, part, bsum);
  scanB_kernel<<<1, 128, 0, stream>>>(bsum, off_f, off_b);
  scanC_kernel<<<2 * SCAN_BLK, 1024, 0, stream>>>(part, bsum, off_f, off_b,
                                                  cur_f, cur_b);
  fill_kernel<<<(N_EDGES + 255) / 256, 256, 0, stream>>>(src, dst, cur_f, cur_b,
                                                         csr_f, csr_b);
  sort_kernel<<<(2 * N_NODES + 255) / 256, 256, 0, stream>>>(off_f, off_b, csr_f,
                                                             csr_b);
  aux_inv_kernel<<<(N_EDGES + 255) / 256, 256, 0, stream>>>(csr_f, inv_f, src_f);
  aux_dst_kernel<<<(N_NODES + 255) / 256, 256, 0, stream>>>(off_f, dst_f);
  aux_remap_kernel<<<(N_EDGES + 255) / 256, 256, 0, stream>>>(inv_f, csr_b);

  // encoders
  encode_kernel<<<(N_NODES * 16 + 255) / 256, 256, 0, stream>>>(
      x, neW1, neb1, neW2, neb2, X, N_NODES);
  encode_perm_kernel<<<(N_EDGES * 16 + 255) / 256, 256, 0, stream>>>(
      e, eeW1, eeb1, eeW2, eeb2, csr_f, E64);

  // layers
  const int NT = (N_NODES + 31) / 32;  // 1563
  for (int l = 0; l < 4; ++l) {
    node_gemm_kernel<<<NT, 320, 0, stream>>>(
        X, A1, A2, A3, B1, B2, bA1, bA2, bA3, bB1, bB2, NA, l);
    edge_update_kernel<<<N_EDGES / 64, 256, 0, stream>>>(NA, B3, bB3, ge, be,
                                                         src_f, dst_f, E64, l);
    aggregate_kernel<<<(N_NODES + 3) / 4, 256, 0, stream>>>(
        NA, E64, off_f, off_b, src_f, csr_b, gh, bh, X, l);
  }

  // predictor
  pred_node_kernel<<<NT, 128, 0, stream>>>(X, pW1, U, V);
  pred_edge_kernel<<<N_EDGES / 64, 256, 0, stream>>>(U, V, E64, csr_f, dst_f,
                                                     pW1, pb1, pW2, pb2,
                                                     (float*)d_out);
}